// Round 1
// baseline (708.415 us; speedup 1.0000x reference)
//
#include <hip/hip_runtime.h>
#include <math.h>

#define NN   128
#define SS   132          // LDS row stride in complex elements (padded)
#define TT   512          // threads per block for FFT kernels
#define NPIX 16384        // 128*128
#define EPT  32           // NPIX / TT

__device__ __forceinline__ float2 cmulf(float2 a, float2 b) {
    return make_float2(a.x * b.x - a.y * b.y, a.x * b.y + a.y * b.x);
}

// ---------- register FFTs (radix-2 DIF + final bit-reversal -> natural order) ----------
template<int SGN>
__device__ __forceinline__ void fft8(float2* f) {
    const float R = 0.70710678118654752f;
    const float WC[4] = {1.f, R, 0.f, -R};
    const float WS[4] = {0.f, R, 1.f, R};   // sin(2*pi*t/8)
    #pragma unroll
    for (int stage = 0; stage < 3; ++stage) {
        const int L = 8 >> stage, half = L >> 1, step = 1 << stage;
        #pragma unroll
        for (int base = 0; base < 8; base += L) {
            #pragma unroll
            for (int j = 0; j < half; ++j) {
                float2 u = f[base + j], v = f[base + half + j];
                f[base + j] = make_float2(u.x + v.x, u.y + v.y);
                float dx = u.x - v.x, dy = u.y - v.y;
                const int t = j * step;
                const float wr = WC[t];
                const float wi = (SGN > 0) ? WS[t] : -WS[t];
                f[base + half + j] = make_float2(dx * wr - dy * wi, dx * wi + dy * wr);
            }
        }
    }
    float2 tmp;
    tmp = f[1]; f[1] = f[4]; f[4] = tmp;
    tmp = f[3]; f[3] = f[6]; f[6] = tmp;
}

template<int SGN>
__device__ __forceinline__ void fft16(float2* f) {
    const float WC[8] = {1.f, 0.92387953251f, 0.70710678119f, 0.38268343236f,
                         0.f, -0.38268343236f, -0.70710678119f, -0.92387953251f};
    const float WS[8] = {0.f, 0.38268343236f, 0.70710678119f, 0.92387953251f,
                         1.f, 0.92387953251f, 0.70710678119f, 0.38268343236f};
    #pragma unroll
    for (int stage = 0; stage < 4; ++stage) {
        const int L = 16 >> stage, half = L >> 1, step = 1 << stage;
        #pragma unroll
        for (int base = 0; base < 16; base += L) {
            #pragma unroll
            for (int j = 0; j < half; ++j) {
                float2 u = f[base + j], v = f[base + half + j];
                f[base + j] = make_float2(u.x + v.x, u.y + v.y);
                float dx = u.x - v.x, dy = u.y - v.y;
                const int t = j * step;
                const float wr = WC[t];
                const float wi = (SGN > 0) ? WS[t] : -WS[t];
                f[base + half + j] = make_float2(dx * wr - dy * wi, dx * wi + dy * wr);
            }
        }
    }
    float2 tmp;
    tmp = f[1];  f[1]  = f[8];  f[8]  = tmp;
    tmp = f[2];  f[2]  = f[4];  f[4]  = tmp;
    tmp = f[3];  f[3]  = f[12]; f[12] = tmp;
    tmp = f[5];  f[5]  = f[10]; f[10] = tmp;
    tmp = f[7];  f[7]  = f[14]; f[14] = tmp;
    tmp = f[11]; f[11] = f[13]; f[13] = tmp;
}

// ---------- in-LDS 2D FFT, 128x128, natural order in and out ----------
// SGN = -1: forward DFT (unnormalized). SGN = +1: inverse DFT (unnormalized, x16384).
// Decomposition per 1D line: n = 16*n1 + n2 ; A[ka,n2]=FFT8 over n1 ; twiddle w128^(n2*ka);
// store at slot 8*n2+ka ; FFT16 over n2 -> slot 8*kb+ka holds freq ka+8*kb == slot index.
template<int SGN>
__device__ void fft2d(float2* F, int tid) {
    const float TW = (float)SGN * 6.28318530717958648f / 128.f;
    // ---- ROW pass, Step A (each row's 16 units live in one wave: no barrier inside) ----
    #pragma unroll
    for (int i = 0; i < 4; ++i) {
        int u = i * TT + tid;
        int r = u >> 4, n2 = u & 15;
        float2 f[8];
        #pragma unroll
        for (int n1 = 0; n1 < 8; ++n1) f[n1] = F[r * SS + n1 * 16 + n2];
        fft8<SGN>(f);
        #pragma unroll
        for (int ka = 0; ka < 8; ++ka) {
            float sn, cs;
            __sincosf(TW * (float)(n2 * ka), &sn, &cs);
            F[r * SS + 8 * n2 + ka] = cmulf(f[ka], make_float2(cs, sn));
        }
    }
    __syncthreads();
    // ---- ROW pass, Step B (in-place per thread) ----
    #pragma unroll
    for (int i = 0; i < 2; ++i) {
        int u = i * TT + tid;
        int r = u >> 3, ka = u & 7;
        float2 g[16];
        #pragma unroll
        for (int n2 = 0; n2 < 16; ++n2) g[n2] = F[r * SS + 8 * n2 + ka];
        fft16<SGN>(g);
        #pragma unroll
        for (int kb = 0; kb < 16; ++kb) F[r * SS + 8 * kb + ka] = g[kb];
    }
    __syncthreads();
    // ---- COL pass, Step A ----
    #pragma unroll
    for (int i = 0; i < 4; ++i) {
        int u = i * TT + tid;
        int c = u >> 4, n2 = u & 15;
        float2 f[8];
        #pragma unroll
        for (int n1 = 0; n1 < 8; ++n1) f[n1] = F[(n1 * 16 + n2) * SS + c];
        fft8<SGN>(f);
        #pragma unroll
        for (int ka = 0; ka < 8; ++ka) {
            float sn, cs;
            __sincosf(TW * (float)(n2 * ka), &sn, &cs);
            F[(8 * n2 + ka) * SS + c] = cmulf(f[ka], make_float2(cs, sn));
        }
    }
    __syncthreads();
    // ---- COL pass, Step B ----
    #pragma unroll
    for (int i = 0; i < 2; ++i) {
        int u = i * TT + tid;
        int c = u >> 3, ka = u & 7;
        float2 g[16];
        #pragma unroll
        for (int n2 = 0; n2 < 16; ++n2) g[n2] = F[(8 * n2 + ka) * SS + c];
        fft16<SGN>(g);
        #pragma unroll
        for (int kb = 0; kb < 16; ++kb) F[(8 * kb + ka) * SS + c] = g[kb];
    }
    __syncthreads();
}

__device__ __forceinline__ float blockReduceSum(float v, float* red, int tid) {
    #pragma unroll
    for (int off = 32; off > 0; off >>= 1) v += __shfl_down(v, off, 64);
    if ((tid & 63) == 0) red[tid >> 6] = v;
    __syncthreads();
    float t = 0.f;
    if (tid == 0) {
        #pragma unroll
        for (int w = 0; w < TT / 64; ++w) t += red[w];
    }
    __syncthreads();
    return t;   // valid on tid 0 only
}

// ---------- K1: Morlet filter bank (natural freq order) + zero coeff accumulators ----------
__global__ void k_psi(float* __restrict__ psi, float* __restrict__ coeffs) {
    int blk = blockIdx.x, tid = threadIdx.x;
    if (blk == 16) {
        for (int i = tid; i < 64 * 11; i += 256) coeffs[i] = 0.f;
        return;
    }
    int j = blk >> 2, l = blk & 3;
    float k0    = 2.35619449019234493f / (float)(1 << j);   // 3*pi/4 / 2^j
    float sigma = 0.8f * (float)(1 << j);
    float s2    = sigma * sigma;
    float theta = 0.78539816339744831f * (float)l;          // pi*l/4
    float k0x = k0 * cosf(theta);
    float k0y = k0 * sinf(theta);
    float beta = expf(-0.5f * s2 * k0 * k0);
    const float FSTEP = 0.04908738521234052f;               // 2*pi/128
    float* dst = psi + (size_t)blk * NPIX;
    for (int i = tid; i < NPIX; i += 256) {
        int kr = i >> 7, kc = i & 127;
        float fr = (float)(kr < 64 ? kr : kr - 128) * FSTEP;
        float fc = (float)(kc < 64 ? kc : kc - 128) * FSTEP;
        float dx = fr - k0x, dy = fc - k0y;
        float g1 = expf(-0.5f * s2 * (dx * dx + dy * dy));
        float g0 = expf(-0.5f * s2 * (fr * fr + fc * fc));
        dst[i] = g1 - beta * g0;
    }
}

// ---------- K2: i_hat = fft2(image), s0 = mean(image) ----------
__global__ __launch_bounds__(TT) void k_ihat(const float* __restrict__ img,
                                             float2* __restrict__ ihat,
                                             float* __restrict__ coeffs) {
    __shared__ float2 F[NN * SS];
    __shared__ float red[TT / 64];
    int tid = threadIdx.x, b = blockIdx.x;
    float acc = 0.f;
    #pragma unroll
    for (int k = 0; k < EPT; ++k) {
        int e = k * TT + tid;
        float v = img[(size_t)b * NPIX + e];
        acc += v;
        F[(e >> 7) * SS + (e & 127)] = make_float2(v, 0.f);
    }
    float tot = blockReduceSum(acc, red, tid);   // barrier inside also covers F writes
    if (tid == 0) coeffs[b * 11 + 0] = tot * (1.f / 16384.f);
    __syncthreads();
    fft2d<-1>(F, tid);
    #pragma unroll
    for (int k = 0; k < EPT; ++k) {
        int e = k * TT + tid;
        ihat[(size_t)b * NPIX + e] = F[(e >> 7) * SS + (e & 127)];
    }
}

// ---------- K3: fused first+second order scattering per (b, j1, l1) ----------
__global__ __launch_bounds__(TT) void k_scatter(const float2* __restrict__ ihat,
                                                const float* __restrict__ psi,
                                                float* __restrict__ coeffs) {
    __shared__ float2 F[NN * SS];
    __shared__ float red[TT / 64];
    int tid = threadIdx.x;
    int x = blockIdx.x;
    int b = x & 63, l1 = (x >> 6) & 3, j1 = x >> 8;
    const float2* ih = ihat + (size_t)b * NPIX;
    const float*  p1 = psi + (size_t)(j1 * 4 + l1) * NPIX;

    // load i_hat * psi_{j1,l1}
    #pragma unroll
    for (int k = 0; k < EPT; ++k) {
        int e = k * TT + tid;
        float2 z = ih[e];
        float  p = p1[e];
        F[(e >> 7) * SS + (e & 127)] = make_float2(z.x * p, z.y * p);
    }
    __syncthreads();
    fft2d<1>(F, tid);                      // unnormalized inverse (x16384)

    // u1 = |.| / 16384, write back as real field, accumulate s1
    float acc = 0.f;
    #pragma unroll
    for (int k = 0; k < EPT; ++k) {
        int e = k * TT + tid;
        int idx = (e >> 7) * SS + (e & 127);
        float2 z = F[idx];
        float m = sqrtf(z.x * z.x + z.y * z.y) * (1.f / 16384.f);
        acc += m;
        F[idx] = make_float2(m, 0.f);
    }
    float tot = blockReduceSum(acc, red, tid);
    if (tid == 0) atomicAdd(&coeffs[b * 11 + 1 + j1], tot * (1.f / 65536.f)); // /(L*N*N)

    fft2d<-1>(F, tid);                     // u1_hat, natural order

    // hold u1_hat in registers
    float2 uh[EPT];
    #pragma unroll
    for (int k = 0; k < EPT; ++k) {
        int e = k * TT + tid;
        uh[k] = F[(e >> 7) * SS + (e & 127)];
    }

    const float inv2 = 2.3283064365386963e-10f;   // 1/(16384*16*16384) = 2^-32
    for (int j2 = j1 + 1; j2 < 4; ++j2) {
        int pair = (j1 == 0) ? (j2 - 1) : ((j1 == 1) ? (j2 + 1) : 5);
        for (int l2 = 0; l2 < 4; ++l2) {
            const float* p2 = psi + (size_t)(j2 * 4 + l2) * NPIX;
            __syncthreads();   // prior iteration's reads of F complete
            #pragma unroll
            for (int k = 0; k < EPT; ++k) {
                int e = k * TT + tid;
                float p = p2[e];
                F[(e >> 7) * SS + (e & 127)] = make_float2(uh[k].x * p, uh[k].y * p);
            }
            __syncthreads();
            fft2d<1>(F, tid);
            float a2 = 0.f;
            #pragma unroll
            for (int k = 0; k < EPT; ++k) {
                int e = k * TT + tid;
                float2 z = F[(e >> 7) * SS + (e & 127)];
                a2 += sqrtf(z.x * z.x + z.y * z.y);
            }
            float t2 = blockReduceSum(a2, red, tid);
            if (tid == 0) atomicAdd(&coeffs[b * 11 + 5 + pair], t2 * inv2);
        }
    }
}

// ---------- K4: tiny MLP head ----------
__global__ void k_mlp(const float* __restrict__ coeffs,
                      const float* __restrict__ w1, const float* __restrict__ b1,
                      const float* __restrict__ w2, const float* __restrict__ b2,
                      float* __restrict__ out) {
    int b = threadIdx.x;
    if (b >= 64) return;
    float c[11];
    #pragma unroll
    for (int i = 0; i < 11; ++i) c[i] = coeffs[b * 11 + i];
    float h[4];
    #pragma unroll
    for (int k = 0; k < 4; ++k) {
        float s = b1[k];
        #pragma unroll
        for (int i = 0; i < 11; ++i) s += w1[k * 11 + i] * c[i];
        h[k] = fmaxf(s, 0.f);
    }
    #pragma unroll
    for (int o = 0; o < 10; ++o) {
        float s = b2[o];
        #pragma unroll
        for (int k = 0; k < 4; ++k) s += w2[o * 4 + k] * h[k];
        out[b * 10 + o] = 1.f / (1.f + expf(-s));
    }
}

extern "C" void kernel_launch(void* const* d_in, const int* in_sizes, int n_in,
                              void* d_out, int out_size, void* d_ws, size_t ws_size,
                              hipStream_t stream) {
    const float* img = (const float*)d_in[0];
    const float* w1  = (const float*)d_in[1];
    const float* b1  = (const float*)d_in[2];
    const float* w2  = (const float*)d_in[3];
    const float* b2  = (const float*)d_in[4];
    float* out = (float*)d_out;

    // workspace layout (floats): psi[16*16384] | ihat[64*16384 float2] | coeffs[64*11]
    float*  ws     = (float*)d_ws;
    float*  psi    = ws;
    float2* ihat   = (float2*)(ws + 16 * NPIX);
    float*  coeffs = ws + 16 * NPIX + 2 * 64 * NPIX;

    hipLaunchKernelGGL(k_psi,     dim3(17),   dim3(256), 0, stream, psi, coeffs);
    hipLaunchKernelGGL(k_ihat,    dim3(64),   dim3(TT),  0, stream, img, ihat, coeffs);
    hipLaunchKernelGGL(k_scatter, dim3(1024), dim3(TT),  0, stream, ihat, psi, coeffs);
    hipLaunchKernelGGL(k_mlp,     dim3(1),    dim3(64),  0, stream, coeffs, w1, b1, w2, b2, out);
}